// Round 3
// baseline (2033.759 us; speedup 1.0000x reference)
//
#include <hip/hip_runtime.h>
#include <cstdint>

#define NE_N   100000
#define NPER_N 50000
#define HD     128
#define OUTD   64
#define NEE    1600000
#define NPE    800000
#define NEP    800000

static inline int ceil_div(long long a, long long b){ return (int)((a + b - 1)/b); }

__device__ __forceinline__ float4 ld4(const float* p){ return *reinterpret_cast<const float4*>(p); }
__device__ __forceinline__ void st4(float* p, float4 v){ *reinterpret_cast<float4*>(p) = v; }
__device__ __forceinline__ float4 f4relu(float4 a){
    a.x=fmaxf(a.x,0.f); a.y=fmaxf(a.y,0.f); a.z=fmaxf(a.z,0.f); a.w=fmaxf(a.w,0.f); return a; }

// ================= GEMM v2: C_seg[N x BN] = A[N x K] @ W_seg[K x BN] (+bias_seg) =================
// 128-row tile, BN-col tile (one weight segment per blockIdx.y). A transposed into LDS
// [k][row] (compute reads are 16-lane broadcasts), W linear [k][col]. KC=32 double-buffered,
// register prefetch: load(c+2) issued right after write(c+1) so HBM latency hides under compute.
template<int K, int BN, bool RELU>
__global__ __launch_bounds__(256)
void gemm2(const float* __restrict__ A, int N,
           const float* __restrict__ Wp0, const float* __restrict__ Wp1, const float* __restrict__ Wp2,
           const float* __restrict__ bp0, const float* __restrict__ bp1, const float* __restrict__ bp2,
           float* __restrict__ Cp0, float* __restrict__ Cp1, float* __restrict__ Cp2)
{
    constexpr int KC = 32;
    constexpr int NK = K / KC;
    constexpr int TN = BN / 16;              // cols per thread: 8 (BN=128) or 4 (BN=64)
    constexpr int WR = (KC*BN) / (256*4);    // W-chunk float4s per thread

    __shared__ float As[2][KC][128];
    __shared__ float Ws[2][KC][BN];

    const float* W; const float* bb; float* C;
    if (blockIdx.y == 0){ W=Wp0; bb=bp0; C=Cp0; }
    else if (blockIdx.y == 1){ W=Wp1; bb=bp1; C=Cp1; }
    else { W=Wp2; bb=bp2; C=Cp2; }

    const int t = threadIdx.x;
    const int row_base = blockIdx.x*128;
    const int sr = t >> 3;          // staging row 0..31 (8 lanes cover 128B of one row)
    const int sc = (t & 7) * 4;     // staging k-offset
    const int tx = t & 15, ty = t >> 4;
    const int c0 = tx * TN;
    const int r0 = ty * 8;

    float4 areg[4], wreg[WR];

    auto load_chunk = [&](int k0){
#pragma unroll
        for (int it=0; it<4; ++it){
            int r = row_base + it*32 + sr;
            if (r > N-1) r = N-1;
            areg[it] = ld4(&A[(size_t)r*K + k0 + sc]);
        }
        const float* Wg = W + (size_t)k0*BN;
#pragma unroll
        for (int i=0;i<WR;i++) wreg[i] = ld4(Wg + (i*256 + t)*4);
    };
    auto write_chunk = [&](int buf){
#pragma unroll
        for (int it=0; it<4; ++it){
            int rr = it*32 + sr;
            As[buf][sc+0][rr] = areg[it].x;
            As[buf][sc+1][rr] = areg[it].y;
            As[buf][sc+2][rr] = areg[it].z;
            As[buf][sc+3][rr] = areg[it].w;
        }
        float* Wl = &Ws[buf][0][0];
#pragma unroll
        for (int i=0;i<WR;i++) st4(Wl + (i*256+t)*4, wreg[i]);
    };

    float acc[8][TN];
#pragma unroll
    for (int i=0;i<8;i++)
#pragma unroll
        for (int j=0;j<TN;j++) acc[i][j]=0.f;

    load_chunk(0);
    write_chunk(0);
    if (NK>1) load_chunk(KC);
    __syncthreads();

    for (int c=0;c<NK;c++){
        int buf = c & 1;
#pragma unroll
        for (int k=0;k<KC;k++){
            float4 a0 = ld4(&As[buf][k][r0]);
            float4 a1 = ld4(&As[buf][k][r0+4]);
            float w[TN];
#pragma unroll
            for (int j=0;j<TN;j+=4){
                float4 wv = ld4(&Ws[buf][k][c0+j]);
                w[j]=wv.x; w[j+1]=wv.y; w[j+2]=wv.z; w[j+3]=wv.w;
            }
            float a[8] = {a0.x,a0.y,a0.z,a0.w,a1.x,a1.y,a1.z,a1.w};
#pragma unroll
            for (int i=0;i<8;i++)
#pragma unroll
                for (int j=0;j<TN;j++)
                    acc[i][j] = fmaf(a[i], w[j], acc[i][j]);
        }
        __syncthreads();
        if (c+1 < NK){
            write_chunk(buf^1);
            if (c+2 < NK) load_chunk((c+2)*KC);
            __syncthreads();
        }
    }

    float bias[TN];
#pragma unroll
    for (int j=0;j<TN;j++) bias[j] = bb ? bb[c0+j] : 0.f;
#pragma unroll
    for (int i=0;i<8;i++){
        int r = row_base + r0 + i;
        if (r < N){
#pragma unroll
            for (int j=0;j<TN;j+=4){
                float4 o;
                o.x = acc[i][j]   + bias[j];
                o.y = acc[i][j+1] + bias[j+1];
                o.z = acc[i][j+2] + bias[j+2];
                o.w = acc[i][j+3] + bias[j+3];
                if (RELU) o = f4relu(o);
                st4(&C[(size_t)r*BN + c0 + j], o);
            }
        }
    }
}

// ================= CSR build =================
__global__ void count_int(const int* __restrict__ dst, int* __restrict__ cnt, int E){
    int i = blockIdx.x*blockDim.x + threadIdx.x;
    if (i < E) atomicAdd(&cnt[dst[i]], 1);
}
__global__ __launch_bounds__(256)
void scan_block(const int* __restrict__ cnt, int* __restrict__ off,
                int* __restrict__ partial, int n){
    __shared__ int sh[256];
    int t = threadIdx.x;
    int base = blockIdx.x*1024 + t*4;
    int v0 = (base  <n)?cnt[base  ]:0;
    int v1 = (base+1<n)?cnt[base+1]:0;
    int v2 = (base+2<n)?cnt[base+2]:0;
    int v3 = (base+3<n)?cnt[base+3]:0;
    int tsum = v0+v1+v2+v3;
    sh[t]=tsum; __syncthreads();
    for (int d=1; d<256; d<<=1){
        int x = (t>=d)? sh[t-d] : 0;
        __syncthreads();
        sh[t] += x;
        __syncthreads();
    }
    int ex = sh[t]-tsum;
    if (base  <n) off[base  ]=ex;
    if (base+1<n) off[base+1]=ex+v0;
    if (base+2<n) off[base+2]=ex+v0+v1;
    if (base+3<n) off[base+3]=ex+v0+v1+v2;
    if (t==255) partial[blockIdx.x]=sh[255];
}
__global__ void scan_partial(int* __restrict__ partial, int nb){
    if (threadIdx.x==0 && blockIdx.x==0){
        int run=0;
        for (int i=0;i<nb;i++){ int v=partial[i]; partial[i]=run; run+=v; }
    }
}
__global__ void add_base(int* __restrict__ off, const int* __restrict__ partial, int n, int total){
    int i = blockIdx.x*blockDim.x + threadIdx.x;
    if (i < n) off[i] += partial[i>>10];
    else if (i == n) off[n] = total;
}
__global__ void fill_csr(const int* __restrict__ src, const int* __restrict__ dst,
                         const int* __restrict__ off, int* __restrict__ cnt,
                         int* __restrict__ csr, int E){
    int i = blockIdx.x*blockDim.x + threadIdx.x;
    if (i >= E) return;
    int d = dst[i];
    int old = atomicAdd(&cnt[d], -1);
    csr[off[d] + old - 1] = src[i];
}

// ================= gather-side aggregation (shfl-broadcast indices) =================
__global__ __launch_bounds__(256)
void agg_emp1(const float* __restrict__ proj_ee, const float* __restrict__ proj_pe,
              const int* __restrict__ ee_off, const int* __restrict__ ee_csr,
              const int* __restrict__ pe_off, const int* __restrict__ pe_csr,
              float* __restrict__ emp1){
    int w    = (blockIdx.x*blockDim.x + threadIdx.x) >> 6;
    int lane = threadIdx.x & 63;
    if (w >= NE_N) return;
    float ax=0.f, ay=0.f;
    int b = ee_off[w], e = ee_off[w+1];
    int dee = e-b;
    for (int cb=b; cb<e; cb+=64){
        int j = cb+lane;
        int myidx = (j<e)? ee_csr[j] : 0;
        int lim = min(64, e-cb);
        for (int q=0;q<lim;q++){
            int s = __shfl(myidx, q, 64);
            float2 v = *reinterpret_cast<const float2*>(&proj_ee[(size_t)s*128 + lane*2]);
            ax += v.x; ay += v.y;
        }
    }
    float s1 = 1.f/fmaxf((float)dee,1.f);
    float bx=0.f, by=0.f;
    b = pe_off[w]; e = pe_off[w+1];
    int dpe = e-b;
    for (int cb=b; cb<e; cb+=64){
        int j = cb+lane;
        int myidx = (j<e)? pe_csr[j] : 0;
        int lim = min(64, e-cb);
        for (int q=0;q<lim;q++){
            int s = __shfl(myidx, q, 64);
            float2 v = *reinterpret_cast<const float2*>(&proj_pe[(size_t)s*128 + lane*2]);
            bx += v.x; by += v.y;
        }
    }
    float s2 = 1.f/fmaxf((float)dpe,1.f);
    float* row = &emp1[(size_t)w*128 + lane*2];
    float2 self = *reinterpret_cast<float2*>(row);
    float2 o;
    o.x = fmaxf(self.x + ax*s1 + bx*s2, 0.f);
    o.y = fmaxf(self.y + ay*s1 + by*s2, 0.f);
    *reinterpret_cast<float2*>(row) = o;
}
__global__ __launch_bounds__(256)
void agg_per1(const float* __restrict__ proj_ep,
              const int* __restrict__ ep_off, const int* __restrict__ ep_csr,
              float* __restrict__ per1){
    int w    = (blockIdx.x*blockDim.x + threadIdx.x) >> 6;
    int lane = threadIdx.x & 63;
    if (w >= NPER_N) return;
    float ax=0.f, ay=0.f;
    int b = ep_off[w], e = ep_off[w+1];
    int deg = e-b;
    for (int cb=b; cb<e; cb+=64){
        int j = cb+lane;
        int myidx = (j<e)? ep_csr[j] : 0;
        int lim = min(64, e-cb);
        for (int q=0;q<lim;q++){
            int s = __shfl(myidx, q, 64);
            float2 v = *reinterpret_cast<const float2*>(&proj_ep[(size_t)s*128 + lane*2]);
            ax += v.x; ay += v.y;
        }
    }
    float s1 = 1.f/fmaxf((float)deg,1.f);
    float* row = &per1[(size_t)w*128 + lane*2];
    float2 self = *reinterpret_cast<float2*>(row);
    float2 o;
    o.x = fmaxf(self.x + ax*s1, 0.f);
    o.y = fmaxf(self.y + ay*s1, 0.f);
    *reinterpret_cast<float2*>(row) = o;
}
__global__ __launch_bounds__(256)
void agg_per2(const float* __restrict__ p2ep,
              const int* __restrict__ ep_off, const int* __restrict__ ep_csr,
              float* __restrict__ out){
    int w    = (blockIdx.x*blockDim.x + threadIdx.x) >> 6;
    int lane = threadIdx.x & 63;
    if (w >= NPER_N) return;
    float a=0.f;
    int b = ep_off[w], e = ep_off[w+1];
    int deg = e-b;
    for (int cb=b; cb<e; cb+=64){
        int j = cb+lane;
        int myidx = (j<e)? ep_csr[j] : 0;
        int lim = min(64, e-cb);
        for (int q=0;q<lim;q++){
            int s = __shfl(myidx, q, 64);
            a += p2ep[(size_t)s*64 + lane];
        }
    }
    float s1 = 1.f/fmaxf((float)deg,1.f);
    out[(size_t)w*64 + lane] += a*s1;
}
// out_emp[d] += GAT_ee(d) + mean_pe(p2pe): alpha computed lane-parallel, broadcast by shfl
__global__ __launch_bounds__(256)
void gat_sage_emp2(const int* __restrict__ ee_off, const int* __restrict__ ee_csr,
                   const int* __restrict__ pe_off, const int* __restrict__ pe_csr,
                   const float* __restrict__ as, const float* __restrict__ ad,
                   const float* __restrict__ zs, const float* __restrict__ p2pe,
                   float* __restrict__ out){
    int w    = (blockIdx.x*blockDim.x + threadIdx.x) >> 6;
    int lane = threadIdx.x & 63;
    if (w >= NE_N) return;

    float acc = 0.f;
    int b = ee_off[w], e = ee_off[w+1];
    if (e > b){
        float add = ad[w];
        float m = -INFINITY;
        for (int j=b+lane; j<e; j+=64){
            float ev = as[ee_csr[j]] + add;
            ev = ev > 0.f ? ev : 0.2f*ev;
            m = fmaxf(m, ev);
        }
        for (int o=32;o;o>>=1) m = fmaxf(m, __shfl_xor(m,o,64));
        float den = 0.f;
        for (int j=b+lane; j<e; j+=64){
            float ev = as[ee_csr[j]] + add;
            ev = ev > 0.f ? ev : 0.2f*ev;
            den += expf(ev - m);
        }
        for (int o=32;o;o>>=1) den += __shfl_xor(den,o,64);
        float invden = 1.f/den;
        for (int cb=b; cb<e; cb+=64){
            int j = cb+lane;
            int s = 0; float al = 0.f;
            if (j < e){
                s = ee_csr[j];
                float ev = as[s] + add;
                ev = ev > 0.f ? ev : 0.2f*ev;
                al = expf(ev - m)*invden;
            }
            int lim = min(64, e-cb);
            for (int q=0;q<lim;q++){
                int   sq = __shfl(s, q, 64);
                float aq = __shfl(al, q, 64);
                acc += zs[(size_t)sq*64 + lane]*aq;
            }
        }
    }
    float a2 = 0.f;
    b = pe_off[w]; e = pe_off[w+1];
    int deg = e-b;
    for (int cb=b; cb<e; cb+=64){
        int j = cb+lane;
        int s = (j<e)? pe_csr[j] : 0;
        int lim = min(64, e-cb);
        for (int q=0;q<lim;q++){
            int sq = __shfl(s,q,64);
            a2 += p2pe[(size_t)sq*64 + lane];
        }
    }
    float s2 = 1.f/fmaxf((float)deg,1.f);
    out[(size_t)w*64 + lane] += acc + a2*s2;
}

// GEMV helpers
__global__ void rowdot64(const float* __restrict__ X, const float* __restrict__ w,
                         float* __restrict__ out, int N){
    int wid  = (blockIdx.x*blockDim.x + threadIdx.x) >> 6;
    int lane = threadIdx.x & 63;
    if (wid >= N) return;
    float v = X[(size_t)wid*64 + lane]*w[lane];
    for (int o=32;o;o>>=1) v += __shfl_xor(v,o,64);
    if (lane==0) out[wid]=v;
}
__global__ void rowdot128(const float* __restrict__ X, const float* __restrict__ w,
                          float* __restrict__ out, int N){
    int wid  = (blockIdx.x*blockDim.x + threadIdx.x) >> 6;
    int lane = threadIdx.x & 63;
    if (wid >= N) return;
    float v = X[(size_t)wid*128 + lane]*w[lane] + X[(size_t)wid*128 + 64 + lane]*w[64+lane];
    for (int o=32;o;o>>=1) v += __shfl_xor(v,o,64);
    if (lane==0) out[wid]=v;
}

__global__ void prep_kernel(const float* __restrict__ Wr_ee, const float* __restrict__ Wr_pe,
                            const float* __restrict__ bl_ee, const float* __restrict__ bl_pe,
                            const float* __restrict__ s2_pe_bl, const float* __restrict__ gat_b,
                            const float* __restrict__ Wdst, const float* __restrict__ adst,
                            float* __restrict__ Wsum, float* __restrict__ bsum1,
                            float* __restrict__ b2sum, float* __restrict__ v){
    int t = threadIdx.x;
    for (int i=t;i<HD*HD;i+=256) Wsum[i]=Wr_ee[i]+Wr_pe[i];
    if (t<HD) bsum1[t]=bl_ee[t]+bl_pe[t];
    if (t<OUTD) b2sum[t]=s2_pe_bl[t]+gat_b[t];
    if (t<HD){
        float s=0.f;
        for (int c=0;c<OUTD;c++) s += Wdst[t*OUTD+c]*adst[c];
        v[t]=s;
    }
}

// ---------------- workspace layout (4-byte units) — identical to round 2 ----------------
constexpr size_t OFF_A     = 0;          // h_emp 12.8M ; later: as @ +0, ad @ +100000
constexpr size_t OFF_B     = 12800000;   // h_per 6.4M
constexpr size_t OFF_C     = 19200000;   // emp1 12.8M
constexpr size_t OFF_D     = 32000000;   // per1 6.4M
constexpr size_t OFF_E     = 38400000;   // proj_ee ; later proj_ep ; later p2pe+p2ep
constexpr size_t OFF_F     = 51200000;   // proj_pe ; later zs
constexpr size_t OFF_WSUM  = 57600000;
constexpr size_t OFF_BSUM1 = 57616384;
constexpr size_t OFF_B2SUM = 57616512;
constexpr size_t OFF_V     = 57616576;
constexpr size_t OFF_EE_CNT = 57700000;
constexpr size_t OFF_EE_OFF = 57800000;
constexpr size_t OFF_PE_CNT = 57900008;
constexpr size_t OFF_PE_OFF = 58000008;
constexpr size_t OFF_EP_CNT = 58100016;
constexpr size_t OFF_EP_OFF = 58150016;
constexpr size_t OFF_PART   = 58200024;
constexpr size_t OFF_EE_CSR = 58200280;
constexpr size_t OFF_PE_CSR = 59800280;
constexpr size_t OFF_EP_CSR = 60600280;

extern "C" void kernel_launch(void* const* d_in, const int* in_sizes, int n_in,
                              void* d_out, int out_size, void* d_ws, size_t ws_size,
                              hipStream_t stream)
{
    const float* x_emp = (const float*)d_in[0];
    const float* x_per = (const float*)d_in[1];
    const int* ee_src = (const int*)d_in[2];
    const int* ee_dst = (const int*)d_in[3];
    const int* pe_src = (const int*)d_in[4];
    const int* pe_dst = (const int*)d_in[5];
    const int* ep_src = (const int*)d_in[6];
    const int* ep_dst = (const int*)d_in[7];
    const float* lin_emp_w=(const float*)d_in[8],  *lin_emp_b=(const float*)d_in[9];
    const float* lin_per_w=(const float*)d_in[10], *lin_per_b=(const float*)d_in[11];
    const float* s1_ee_Wl=(const float*)d_in[12], *s1_ee_bl=(const float*)d_in[13], *s1_ee_Wr=(const float*)d_in[14];
    const float* s1_pe_Wl=(const float*)d_in[15], *s1_pe_bl=(const float*)d_in[16], *s1_pe_Wr=(const float*)d_in[17];
    const float* s1_ep_Wl=(const float*)d_in[18], *s1_ep_bl=(const float*)d_in[19], *s1_ep_Wr=(const float*)d_in[20];
    const float* gat_Wsrc=(const float*)d_in[21], *gat_Wdst=(const float*)d_in[22];
    const float* gat_asrc=(const float*)d_in[23], *gat_adst=(const float*)d_in[24], *gat_b=(const float*)d_in[25];
    const float* s2_pe_Wl=(const float*)d_in[26], *s2_pe_bl=(const float*)d_in[27], *s2_pe_Wr=(const float*)d_in[28];
    const float* s2_ep_Wl=(const float*)d_in[29], *s2_ep_bl=(const float*)d_in[30], *s2_ep_Wr=(const float*)d_in[31];

    float* ws = (float*)d_ws;
    int*   wi = (int*)d_ws;
    float* out_emp = (float*)d_out;
    float* out_per = out_emp + (size_t)NE_N*OUTD;

    float* h_emp = ws + OFF_A;
    float* h_per = ws + OFF_B;
    float* emp1  = ws + OFF_C;
    float* per1  = ws + OFF_D;
    float* proj_ee = ws + OFF_E;     // also proj_ep (after agg_emp1)
    float* proj_pe = ws + OFF_F;
    float* p2pe  = ws + OFF_E;
    float* p2ep  = ws + OFF_E + 3200000;
    float* zs    = ws + OFF_F;
    float* a_s   = ws + OFF_A;
    float* a_d   = ws + OFF_A + 100000;
    float* Wsum  = ws + OFF_WSUM;
    float* bsum1 = ws + OFF_BSUM1;
    float* b2sum = ws + OFF_B2SUM;
    float* vvec  = ws + OFF_V;

    int* ee_cnt = wi + OFF_EE_CNT; int* ee_off = wi + OFF_EE_OFF; int* ee_csr = wi + OFF_EE_CSR;
    int* pe_cnt = wi + OFF_PE_CNT; int* pe_off = wi + OFF_PE_OFF; int* pe_csr = wi + OFF_PE_CSR;
    int* ep_cnt = wi + OFF_EP_CNT; int* ep_off = wi + OFF_EP_OFF; int* ep_csr = wi + OFF_EP_CSR;
    int* part   = wi + OFF_PART;

    const int GE = ceil_div(NE_N,128), GP = ceil_div(NPER_N,128);

    // ---- CSR build ----
    hipMemsetAsync(ee_cnt, 0, 100000*sizeof(int), stream);
    hipMemsetAsync(pe_cnt, 0, 100000*sizeof(int), stream);
    hipMemsetAsync(ep_cnt, 0,  50000*sizeof(int), stream);

    prep_kernel<<<1,256,0,stream>>>(s1_ee_Wr, s1_pe_Wr, s1_ee_bl, s1_pe_bl,
                                    s2_pe_bl, gat_b, gat_Wdst, gat_adst,
                                    Wsum, bsum1, b2sum, vvec);

    count_int<<<ceil_div(NEE,256),256,0,stream>>>(ee_dst, ee_cnt, NEE);
    count_int<<<ceil_div(NPE,256),256,0,stream>>>(pe_dst, pe_cnt, NPE);
    count_int<<<ceil_div(NEP,256),256,0,stream>>>(ep_dst, ep_cnt, NEP);

    {   int nb = ceil_div(NE_N,1024);
        scan_block<<<nb,256,0,stream>>>(ee_cnt, ee_off, part, NE_N);
        scan_partial<<<1,64,0,stream>>>(part, nb);
        add_base<<<ceil_div(NE_N+1,256),256,0,stream>>>(ee_off, part, NE_N, NEE);
        fill_csr<<<ceil_div(NEE,256),256,0,stream>>>(ee_src, ee_dst, ee_off, ee_cnt, ee_csr, NEE);
    }
    {   int nb = ceil_div(NE_N,1024);
        scan_block<<<nb,256,0,stream>>>(pe_cnt, pe_off, part, NE_N);
        scan_partial<<<1,64,0,stream>>>(part, nb);
        add_base<<<ceil_div(NE_N+1,256),256,0,stream>>>(pe_off, part, NE_N, NPE);
        fill_csr<<<ceil_div(NPE,256),256,0,stream>>>(pe_src, pe_dst, pe_off, pe_cnt, pe_csr, NPE);
    }
    {   int nb = ceil_div(NPER_N,1024);
        scan_block<<<nb,256,0,stream>>>(ep_cnt, ep_off, part, NPER_N);
        scan_partial<<<1,64,0,stream>>>(part, nb);
        add_base<<<ceil_div(NPER_N+1,256),256,0,stream>>>(ep_off, part, NPER_N, NEP);
        fill_csr<<<ceil_div(NEP,256),256,0,stream>>>(ep_src, ep_dst, ep_off, ep_cnt, ep_csr, NEP);
    }

    // ---- input projections ----
    gemm2<64,128,true><<<dim3(GE,1),256,0,stream>>>(x_emp, NE_N,
        lin_emp_w, lin_emp_w, lin_emp_w, lin_emp_b, lin_emp_b, lin_emp_b,
        h_emp, h_emp, h_emp);
    gemm2<32,128,true><<<dim3(GP,1),256,0,stream>>>(x_per, NPER_N,
        lin_per_w, lin_per_w, lin_per_w, lin_per_b, lin_per_b, lin_per_b,
        h_per, h_per, h_per);

    // ---- conv1 ----
    // G3a: h_emp @ [Wsum | s1_ee_Wl] -> [emp1_base(+bsum1), proj_ee]
    gemm2<128,128,false><<<dim3(GE,2),256,0,stream>>>(h_emp, NE_N,
        Wsum, s1_ee_Wl, s1_ee_Wl, bsum1, nullptr, nullptr,
        emp1, proj_ee, proj_ee);
    // G4: h_per @ [s1_pe_Wl | s1_ep_Wr] -> [proj_pe, per1_base(+bl_ep)]
    gemm2<128,128,false><<<dim3(GP,2),256,0,stream>>>(h_per, NPER_N,
        s1_pe_Wl, s1_ep_Wr, s1_ep_Wr, nullptr, s1_ep_bl, nullptr,
        proj_pe, per1, per1);
    agg_emp1<<<ceil_div((long long)NE_N*64,256),256,0,stream>>>(proj_ee, proj_pe, ee_off, ee_csr, pe_off, pe_csr, emp1);

    // G3b: h_emp @ s1_ep_Wl -> proj_ep (reuses proj_ee slot)
    gemm2<128,128,false><<<dim3(GE,1),256,0,stream>>>(h_emp, NE_N,
        s1_ep_Wl, s1_ep_Wl, s1_ep_Wl, nullptr, nullptr, nullptr,
        proj_ee, proj_ee, proj_ee);
    agg_per1<<<ceil_div((long long)NPER_N*64,256),256,0,stream>>>(proj_ee, ep_off, ep_csr, per1);

    // ---- conv2 ----
    // G5: emp1 @ [gat_Wsrc | s2_ep_Wl | s2_pe_Wr] -> [zs, p2ep, emp2_base(+b2sum)]
    gemm2<128,64,false><<<dim3(GE,3),256,0,stream>>>(emp1, NE_N,
        gat_Wsrc, s2_ep_Wl, s2_pe_Wr, nullptr, nullptr, b2sum,
        zs, p2ep, out_emp);
    rowdot64 <<<ceil_div(NE_N,4),256,0,stream>>>(zs,   gat_asrc, a_s, NE_N);
    rowdot128<<<ceil_div(NE_N,4),256,0,stream>>>(emp1, vvec,     a_d, NE_N);
    // G6: per1 @ [s2_pe_Wl | s2_ep_Wr] -> [p2pe, per2_base(+bl)]
    gemm2<128,64,false><<<dim3(GP,2),256,0,stream>>>(per1, NPER_N,
        s2_pe_Wl, s2_ep_Wr, s2_ep_Wr, nullptr, s2_ep_bl, nullptr,
        p2pe, out_per, out_per);

    gat_sage_emp2<<<ceil_div((long long)NE_N*64,256),256,0,stream>>>(ee_off, ee_csr, pe_off, pe_csr, a_s, a_d, zs, p2pe, out_emp);
    agg_per2<<<ceil_div((long long)NPER_N*64,256),256,0,stream>>>(p2ep, ep_off, ep_csr, out_per);
}